// Round 9
// baseline (10350.018 us; speedup 1.0000x reference)
//
#include <hip/hip_runtime.h>

#define V 256
#define H 2048
#define A 512
#define S 512
#define NBLK 128
#define NTHR 512
#define CH 64            // floats per h/e chunk slot (256B spread)
#define CH2 16           // floats per dp-accumulator slot (64B line)
#define HPH (512*CH)     // h-exchange floats per phase (512 x 16B chunks)
#define EPH (128*CH)     // e-exchange floats per phase (128 x 16B chunks)
#define DPH (512*CH2)    // dp-accumulator floats per phase
#define SENTU 0x7FC00000u
#define SENT64 0x7FC000007FC00000ULL

typedef float f32x4 __attribute__((ext_vector_type(4)));
typedef float f32x2 __attribute__((ext_vector_type(2)));
typedef unsigned long long u64;

// ---- plain coherent loads (poll side) ----
__device__ __forceinline__ f32x4 ld_cg4(const float* p) {
    f32x4 r;
    asm volatile("global_load_dwordx4 %0, %1, off sc0 sc1\n\ts_waitcnt vmcnt(0)"
                 : "=&v"(r) : "v"(p) : "memory");
    return r;
}
__device__ __forceinline__ f32x4 poll4(const float* p) {
    f32x4 r = ld_cg4(p);
    while (__float_as_uint(r.x) == SENTU || __float_as_uint(r.y) == SENTU ||
           __float_as_uint(r.z) == SENTU || __float_as_uint(r.w) == SENTU)
        r = ld_cg4(p);
    return r;
}
__device__ __forceinline__ unsigned ld_cg1u(const unsigned* p) {
    unsigned r;
    asm volatile("global_load_dword %0, %1, off sc0 sc1\n\ts_waitcnt vmcnt(0)"
                 : "=&v"(r) : "v"(p) : "memory");
    return r;
}
__device__ __forceinline__ void ld_cg8(const float* p0, const float* p1, const float* p2, const float* p3,
                                       const float* p4, const float* p5, const float* p6, const float* p7,
                                       float o[8]) {
    float a0,a1,a2,a3,a4,a5,a6,a7;
    asm volatile(
        "global_load_dword %0, %8, off sc0 sc1\n\t"
        "global_load_dword %1, %9, off sc0 sc1\n\t"
        "global_load_dword %2, %10, off sc0 sc1\n\t"
        "global_load_dword %3, %11, off sc0 sc1\n\t"
        "global_load_dword %4, %12, off sc0 sc1\n\t"
        "global_load_dword %5, %13, off sc0 sc1\n\t"
        "global_load_dword %6, %14, off sc0 sc1\n\t"
        "global_load_dword %7, %15, off sc0 sc1\n\t"
        "s_waitcnt vmcnt(0)"
        : "=&v"(a0),"=&v"(a1),"=&v"(a2),"=&v"(a3),"=&v"(a4),"=&v"(a5),"=&v"(a6),"=&v"(a7)
        : "v"(p0),"v"(p1),"v"(p2),"v"(p3),"v"(p4),"v"(p5),"v"(p6),"v"(p7)
        : "memory");
    o[0]=a0;o[1]=a1;o[2]=a2;o[3]=a3;o[4]=a4;o[5]=a5;o[6]=a6;o[7]=a7;
}

// ---- atomic publish side (executes at coherence point; immediate visibility) ----
__device__ __forceinline__ void vm_drain() { asm volatile("s_waitcnt vmcnt(0)" ::: "memory"); }
__device__ __forceinline__ void ax_st64(u64* p, u64 v) {
    (void)__hip_atomic_exchange(p, v, __ATOMIC_RELAXED, __HIP_MEMORY_SCOPE_AGENT);
}
__device__ __forceinline__ void ax_st32(unsigned* p, unsigned v) {
    (void)__hip_atomic_exchange(p, v, __ATOMIC_RELAXED, __HIP_MEMORY_SCOPE_AGENT);
}
__device__ __forceinline__ float ga_addf(float* p, float v) {
    return __hip_atomic_fetch_add(p, v, __ATOMIC_RELAXED, __HIP_MEMORY_SCOPE_AGENT);
}
__device__ __forceinline__ unsigned ga_addu(unsigned* p, unsigned v) {
    return __hip_atomic_fetch_add(p, v, __ATOMIC_RELAXED, __HIP_MEMORY_SCOPE_AGENT);
}
__device__ __forceinline__ u64 pack2(float a, float b) {
    return ((u64)__float_as_uint(b) << 32) | (u64)__float_as_uint(a);
}

__global__ void init_ex(unsigned* sent, int n_sent, unsigned* zero, int n_zero, unsigned* cnt) {
    int i = blockIdx.x * blockDim.x + threadIdx.x;
    if (i < n_sent) sent[i] = SENTU;
    if (i < n_zero) zero[i] = 0u;
    if (i == 0) { cnt[0] = NBLK; cnt[64] = 0u; cnt[128] = 0u; }
}

// ---------------- generic NT GEMM (unchanged) ----------------
__global__ __launch_bounds__(256) void gemm_nt(
    const float* __restrict__ Amat, int lda,
    const float* __restrict__ Bmat, int ldb,
    float* __restrict__ C, int ldc,
    const float* __restrict__ bias, int M, int N, int K)
{
    __shared__ float As[16][68];
    __shared__ float Bs[16][68];
    const int tid = threadIdx.x;
    const int tx = tid & 15;
    const int ty = tid >> 4;
    const int m0 = blockIdx.y * 64;
    const int n0 = blockIdx.x * 64;
    const int lr = tid >> 2;
    const int lk = (tid & 3) * 4;

    float acc[4][4] = {};
    for (int k0 = 0; k0 < K; k0 += 16) {
        float4 av = *(const float4*)(Amat + (size_t)(m0 + lr) * lda + k0 + lk);
        float4 bv = *(const float4*)(Bmat + (size_t)(n0 + lr) * ldb + k0 + lk);
        __syncthreads();
        As[lk+0][lr] = av.x; As[lk+1][lr] = av.y; As[lk+2][lr] = av.z; As[lk+3][lr] = av.w;
        Bs[lk+0][lr] = bv.x; Bs[lk+1][lr] = bv.y; Bs[lk+2][lr] = bv.z; Bs[lk+3][lr] = bv.w;
        __syncthreads();
        #pragma unroll
        for (int k = 0; k < 16; ++k) {
            float a4[4], b4[4];
            #pragma unroll
            for (int i = 0; i < 4; ++i) a4[i] = As[k][ty*4+i];
            #pragma unroll
            for (int j = 0; j < 4; ++j) b4[j] = Bs[k][tx*4+j];
            #pragma unroll
            for (int i = 0; i < 4; ++i)
                #pragma unroll
                for (int j = 0; j < 4; ++j) acc[i][j] += a4[i] * b4[j];
        }
    }
    #pragma unroll
    for (int i = 0; i < 4; ++i) {
        const int m = m0 + ty*4 + i;
        #pragma unroll
        for (int j = 0; j < 4; ++j) {
            const int n = n0 + tx*4 + j;
            float v = acc[i][j];
            if (bias) v += bias[n];
            C[(size_t)m * ldc + n] = v;
        }
    }
}

// ---------------- dp0: dp for decoder step 0 (from last encoder state) ----------------
__global__ __launch_bounds__(512) void dp0_kernel(
    const float* __restrict__ Wa_dec, const float* __restrict__ hN, float* __restrict__ dpacc)
{
    const int wid = threadIdx.x >> 6, lane = threadIdx.x & 63;
    const int a   = blockIdx.x * 8 + wid;      // 0..511
    const f32x4* w4 = (const f32x4*)(Wa_dec + (size_t)a * H);
    const f32x4* h4 = (const f32x4*)hN;
    float acc = 0.f;
    #pragma unroll
    for (int k = 0; k < 8; ++k) {
        f32x4 w = w4[lane + 64*k];
        f32x4 h = h4[lane + 64*k];
        acc += w.x*h.x + w.y*h.y + w.z*h.z + w.w*h.w;
    }
    #pragma unroll
    for (int off = 32; off; off >>= 1) acc += __shfl_down(acc, off);
    if (lane == 0) ax_st32((unsigned*)(dpacc + (size_t)a*CH2), __float_as_uint(acc));
}

// ---------------- persistent encoder scan ----------------
__global__ __launch_bounds__(NTHR, 2) void enc_scan(
    const float* __restrict__ W_enc, const float* __restrict__ accx,
    float* __restrict__ states, float* __restrict__ hex)
{
    __shared__ __align__(16) float hs[H];
    const int tid = threadIdx.x;
    const int wid = tid >> 6, lane = tid & 63;
    const int w   = blockIdx.x * 8 + wid;     // 0..1023, rows 2w,2w+1
    const int r0  = 2*w, r1 = r0 + 1;
    const int slot = (w >> 1)*CH + (w & 1)*2;

    f32x4 we0[8], we1[8];
    #pragma unroll
    for (int k = 0; k < 8; ++k) {
        we0[k] = *(const f32x4*)(W_enc + (size_t)r0*(V+H) + V + 4*(lane + 64*k));
        we1[k] = *(const f32x4*)(W_enc + (size_t)r1*(V+H) + V + 4*(lane + 64*k));
    }

    // t = 0
    if (lane == 0) {
        float h0 = tanhf(accx[r0]), h1 = tanhf(accx[r1]);
        vm_drain();
        ax_st64((u64*)(hex + 0*HPH + slot), pack2(h0, h1));
        states[r0] = h0; states[r1] = h1;
    }

    for (int t = 1; t < S; ++t) {
        float ax0 = accx[(size_t)t*H + r0];    // broadcast load, all lanes
        float ax1 = accx[(size_t)t*H + r1];
        ((f32x4*)hs)[tid] = poll4(hex + ((t-1)%3)*HPH + tid*CH);
        __syncthreads();

        const f32x4* h4 = (const f32x4*)hs;
        float a0 = 0.f, a1 = 0.f;
        #pragma unroll
        for (int k = 0; k < 8; ++k) {
            f32x4 hv = h4[lane + 64*k];
            a0 += we0[k].x*hv.x + we0[k].y*hv.y + we0[k].z*hv.z + we0[k].w*hv.w;
            a1 += we1[k].x*hv.x + we1[k].y*hv.y + we1[k].z*hv.z + we1[k].w*hv.w;
        }
        #pragma unroll
        for (int off = 32; off; off >>= 1) { a0 += __shfl_down(a0, off); a1 += __shfl_down(a1, off); }
        if (lane == 0) {
            float h0 = tanhf(a0 + ax0);
            float h1 = tanhf(a1 + ax1);
            vm_drain();                                      // prior reset at IC before publish
            ax_st64((u64*)(hex + (t%3)*HPH + slot), pack2(h0, h1));
            // off critical path:
            states[(size_t)t*H + r0] = h0; states[(size_t)t*H + r1] = h1;
            ax_st64((u64*)(hex + ((t+1)%3)*HPH + slot), SENT64);
        }
    }
}

// ---------------- persistent decoder scan: 2 hops/step (dp via concurrent accumulate) ----------------
__global__ __launch_bounds__(NTHR, 1) void dec_scan(
    const float* __restrict__ Wa_dec, const float* __restrict__ W_dec,
    const float* __restrict__ enc_proj, const float* __restrict__ v_a,
    const float* __restrict__ WcT, const float* __restrict__ accx,
    const float* __restrict__ enc_states, float* __restrict__ h_dec,
    float* __restrict__ hexd, float* __restrict__ eex,
    float* __restrict__ dpacc, unsigned* __restrict__ cnt)
{
    __shared__ __align__(16) float hs[H];
    __shared__ __align__(16) float es[S];
    __shared__ float dpl[A];
    __shared__ float zred[8];
    const int tid = threadIdx.x;
    const int wid = tid >> 6, lane = tid & 63;
    const int bid = blockIdx.x;
    const int w   = bid * 8 + wid;            // 0..1023, rows 2w,2w+1
    const int r0  = 2*w, r1 = r0 + 1;
    const int hslot = (w >> 1)*CH + (w & 1)*2;
    const bool attn = ((w & 1) == 0);         // even waves own attn row s_row = w>>1
    const int s_row = w >> 1;                 // block b owns s_rows 4b..4b+3 (its e-chunk = b)

    // register-resident weights
    f32x4 wh0[8], wh1[8], wc0[2], wc1[2];
    float ep_r[8], va_r[8], wac0[8], wac1[8];
    #pragma unroll
    for (int k = 0; k < 8; ++k) {
        wh0[k] = *(const f32x4*)(W_dec + (size_t)r0*(V+2*H) + V + H + 4*(lane + 64*k));
        wh1[k] = *(const f32x4*)(W_dec + (size_t)r1*(V+2*H) + V + H + 4*(lane + 64*k));
        // Wa columns r0, r1 at rows a = lane+64k (for partial-dp accumulate)
        wac0[k] = Wa_dec[(size_t)(lane + 64*k)*H + r0];
        wac1[k] = Wa_dec[(size_t)(lane + 64*k)*H + r1];
        ep_r[k] = 0.f; va_r[k] = 0.f;
    }
    #pragma unroll
    for (int k = 0; k < 2; ++k) {
        wc0[k] = *(const f32x4*)(WcT + (size_t)r0*S + 4*(lane + 64*k));
        wc1[k] = *(const f32x4*)(WcT + (size_t)r1*S + 4*(lane + 64*k));
    }
    if (attn) {
        #pragma unroll
        for (int k = 0; k < 8; ++k) {
            ep_r[k] = enc_proj[(size_t)s_row*A + lane + 64*k];
            va_r[k] = v_a[lane + 64*k];
        }
    }
    const f32x4* hs4 = (const f32x4*)hs;
    const f32x4* es4 = (const f32x4*)es;

    for (int t = 0; t < S; ++t) {
        const int ph  = t % 3;
        const int phn = (t+1) % 3;
        const int php = (t+2) % 3;   // == (t-1)%3

        // ---- A: stage h_{t-1} ----
        if (t == 0) ((f32x4*)hs)[tid] = ((const f32x4*)(enc_states + (size_t)(S-1)*H))[tid];
        else        ((f32x4*)hs)[tid] = poll4(hexd + php*HPH + tid*CH);
        __syncthreads();                                   // sync1

        // ---- B: attn waves: dp-ready wait -> read dp -> e -> publish (critical) ----
        if (attn) {
            float* dpb = dpacc + ph*DPH;
            const float* q0 = dpb + (size_t)(lane      )*CH2;
            const float* q1 = dpb + (size_t)(lane +  64)*CH2;
            const float* q2 = dpb + (size_t)(lane + 128)*CH2;
            const float* q3 = dpb + (size_t)(lane + 192)*CH2;
            const float* q4 = dpb + (size_t)(lane + 256)*CH2;
            const float* q5 = dpb + (size_t)(lane + 320)*CH2;
            const float* q6 = dpb + (size_t)(lane + 384)*CH2;
            const float* q7 = dpb + (size_t)(lane + 448)*CH2;
            const unsigned* cp = cnt + ph*64;
            while (ld_cg1u(cp) < NBLK) {}
            float dpv[8];
            ld_cg8(q0,q1,q2,q3,q4,q5,q6,q7, dpv);
            float e_ = 0.f;
            #pragma unroll
            for (int k = 0; k < 8; ++k) e_ += va_r[k] * tanhf(ep_r[k] + dpv[k]);
            #pragma unroll
            for (int off = 32; off; off >>= 1) e_ += __shfl_xor(e_, off);
            if (lane == 0)
                ax_st32((unsigned*)(eex + ph*EPH + (s_row>>2)*CH + (s_row&3)),
                        __float_as_uint(expf(e_)));
        }

        // ---- W_h dots (all waves; overlaps e-hop) ----
        float aH0 = 0.f, aH1 = 0.f;
        #pragma unroll
        for (int k = 0; k < 8; ++k) {
            f32x4 hv = hs4[lane + 64*k];
            aH0 += wh0[k].x*hv.x + wh0[k].y*hv.y + wh0[k].z*hv.z + wh0[k].w*hv.w;
            aH1 += wh1[k].x*hv.x + wh1[k].y*hv.y + wh1[k].z*hv.z + wh1[k].w*hv.w;
        }
        #pragma unroll
        for (int off = 32; off; off >>= 1) { aH0 += __shfl_xor(aH0, off); aH1 += __shfl_xor(aH1, off); }

        // ---- C: poll e (128 chunks) ----
        if (tid < 128) ((f32x4*)es)[tid] = poll4(eex + ph*EPH + tid*CH);
        __syncthreads();                                   // sync2

        // ---- D: Z, ctx, h_new, publish ----
        float z = es[tid];
        #pragma unroll
        for (int off = 32; off; off >>= 1) z += __shfl_xor(z, off);
        if (lane == 0) zred[wid] = z;
        __syncthreads();                                   // syncZ
        const float Z = zred[0]+zred[1]+zred[2]+zred[3]+zred[4]+zred[5]+zred[6]+zred[7];

        float c0 = 0.f, c1 = 0.f;
        #pragma unroll
        for (int k = 0; k < 2; ++k) {
            f32x4 ev = es4[lane + 64*k];
            c0 += wc0[k].x*ev.x + wc0[k].y*ev.y + wc0[k].z*ev.z + wc0[k].w*ev.w;
            c1 += wc1[k].x*ev.x + wc1[k].y*ev.y + wc1[k].z*ev.z + wc1[k].w*ev.w;
        }
        #pragma unroll
        for (int off = 32; off; off >>= 1) { c0 += __shfl_xor(c0, off); c1 += __shfl_xor(c1, off); }

        const float Zi = 1.f / Z;
        const float ax0 = accx[(size_t)t*H + r0];          // broadcast loads
        const float ax1 = accx[(size_t)t*H + r1];
        const float h0 = tanhf(ax0 + aH0 + c0*Zi);         // all lanes (needed for dp partial)
        const float h1 = tanhf(ax1 + aH1 + c1*Zi);
        if (lane == 0) {
            vm_drain();                                    // prior resets at IC before publish
            ax_st64((u64*)(hexd + ph*HPH + hslot), pack2(h0, h1));
            f32x2 hv; hv.x = h0; hv.y = h1;
            *(f32x2*)(h_dec + (size_t)t*H + r0) = hv;      // off critical path
        }

        // ---- E (off critical path): dp contribution for step t+1 ----
        if (t < S-1) {
            dpl[tid] = 0.f;
            __syncthreads();
            #pragma unroll
            for (int k = 0; k < 8; ++k)
                atomicAdd(&dpl[lane + 64*k], wac0[k]*h0 + wac1[k]*h1);
            __syncthreads();
            (void)ga_addf(dpacc + phn*DPH + (size_t)tid*CH2, dpl[tid]);
            vm_drain();                                    // per-wave: own adds at IC
            __syncthreads();                               // all waves' adds at IC
            if (tid == 0) (void)ga_addu(cnt + phn*64, 1u);
        }

        // ---- resets (all proven-consumed phases) ----
        if (lane == 0) ax_st64((u64*)(hexd + phn*HPH + hslot), SENT64);          // h phase, read at t-1
        if (t > 0 && attn && lane == 0)
            ax_st32((unsigned*)(eex + php*EPH + (s_row>>2)*CH + (s_row&3)), SENTU); // e phase, read at t-1
        if (tid < 4) ax_st32((unsigned*)(dpacc + ph*DPH + (size_t)(4*bid+tid)*CH2), 0u); // dp slots, read this step
        if (bid == 0 && tid == 0) ax_st32(cnt + ph*64, 0u);                      // counter, read this step
    }
}

extern "C" void kernel_launch(void* const* d_in, const int* in_sizes, int n_in,
                              void* d_out, int out_size, void* d_ws, size_t ws_size,
                              hipStream_t stream) {
    const float* x_enc  = (const float*)d_in[0];
    const float* x_dec  = (const float*)d_in[1];
    const float* W_enc  = (const float*)d_in[2];
    const float* b_enc  = (const float*)d_in[3];
    const float* Wa_enc = (const float*)d_in[4];
    const float* Wa_dec = (const float*)d_in[5];
    const float* v_a    = (const float*)d_in[6];
    const float* W_dec  = (const float*)d_in[7];
    const float* b_dec  = (const float*)d_in[8];
    const float* W_out  = (const float*)d_in[9];
    const float* b_out  = (const float*)d_in[10];
    float* out = (float*)d_out;

    float* ws         = (float*)d_ws;
    float* accx_enc   = ws;                          // S*H
    float* enc_states = accx_enc + (size_t)S*H;      // S*H
    float* enc_proj   = enc_states + (size_t)S*H;    // S*A
    float* WcT        = enc_proj + (size_t)S*A;      // H*S
    float* accx_dec   = WcT + (size_t)H*S;           // S*H
    float* h_dec      = accx_dec + (size_t)S*H;      // S*H
    float* hex_e      = h_dec + (size_t)S*H;         // 3*HPH  (sentinel-init)
    float* hex_d      = hex_e + 3*HPH;               // 3*HPH  (sentinel-init)
    float* e_ex       = hex_d + 3*HPH;               // 3*EPH  (sentinel-init)
    float* dpacc      = e_ex + 3*EPH;                // 3*DPH  (zero-init)
    unsigned* cnt     = (unsigned*)(dpacc + 3*DPH);  // 3*64 ints
    const int n_sent = 3*HPH*2 + 3*EPH;              // hex_e + hex_d + e_ex
    const int n_zero = 3*DPH;

    dim3 b256(256);

    init_ex<<<dim3((n_sent + 255)/256), b256, 0, stream>>>(
        (unsigned*)hex_e, n_sent, (unsigned*)dpacc, n_zero, cnt);

    // accx_enc = x_enc @ W_enc[:, :V].T + b_enc
    gemm_nt<<<dim3(H/64, S/64), b256, 0, stream>>>(x_enc, V, W_enc, V+H, accx_enc, H, b_enc, S, H, V);
    // accx_dec = x_dec @ W_dec[:, :V].T + b_dec
    gemm_nt<<<dim3(H/64, S/64), b256, 0, stream>>>(x_dec, V, W_dec, V+2*H, accx_dec, H, b_dec, S, H, V);

    // encoder scan
    {
        const float* We = W_enc; const float* ax = accx_enc; float* st = enc_states; float* hx = hex_e;
        void* args[] = { &We, &ax, &st, &hx };
        hipLaunchCooperativeKernel((void*)enc_scan, dim3(NBLK), dim3(NTHR), args, 0, stream);
    }

    // enc_proj = enc_states @ Wa_enc.T
    gemm_nt<<<dim3(A/64, S/64), b256, 0, stream>>>(enc_states, H, Wa_enc, H, enc_proj, A, nullptr, S, A, H);
    // WcT[i][s] = W_c[i]·enc_states[s]
    gemm_nt<<<dim3(S/64, H/64), b256, 0, stream>>>(W_dec + V, V+2*H, enc_states, H, WcT, S, nullptr, H, S, H);
    // dp for decoder t=0 (phase 0; counter[0] preset to NBLK by init)
    {
        dp0_kernel<<<dim3(64), dim3(512), 0, stream>>>(Wa_dec, enc_states + (size_t)(S-1)*H, dpacc);
    }

    // decoder scan
    {
        const float* wa = Wa_dec; const float* wd = W_dec; const float* epj = enc_proj;
        const float* vv = v_a; const float* wc = WcT; const float* ax = accx_dec;
        const float* est = enc_states; float* hd = h_dec;
        float* hx = hex_d; float* ex = e_ex; float* dpa = dpacc; unsigned* cc = cnt;
        void* args[] = { &wa, &wd, &epj, &vv, &wc, &ax, &est, &hd, &hx, &ex, &dpa, &cc };
        hipLaunchCooperativeKernel((void*)dec_scan, dim3(NBLK), dim3(NTHR), args, 0, stream);
    }

    // logits = h_dec @ W_out.T + b_out
    gemm_nt<<<dim3(V/64, S/64), b256, 0, stream>>>(h_dec, H, W_out, H, out, V, b_out, S, V, H);
}

// Round 10
// 6382.590 us; speedup vs baseline: 1.6216x; 1.6216x over previous
//
#include <hip/hip_runtime.h>

#define V 256
#define H 2048
#define A 512
#define S 512
#define NBLK 128
#define NTHR 512
#define CH 64            // floats per chunk slot (256B spread); h-chunks use first 16
#define HPH (128*CH)     // h-exchange floats per phase (128 x 64B packed chunks)
#define DPH (128*CH)     // dp/e-exchange floats per phase (128 x 16B chunks)
#define SENTU 0x7FC00000u

typedef float f32x4 __attribute__((ext_vector_type(4)));
typedef float f32x2 __attribute__((ext_vector_type(2)));

// ---- coherent poll/publish primitives (NaN-sentinel self-tagging) ----
__device__ __forceinline__ f32x4 ld_cg4(const float* p) {
    f32x4 r;
    asm volatile("global_load_dwordx4 %0, %1, off sc0 sc1\n\ts_waitcnt vmcnt(0)"
                 : "=&v"(r) : "v"(p) : "memory");
    return r;
}
__device__ __forceinline__ f32x4 poll4(const float* p) {
    f32x4 r = ld_cg4(p);
    while (__float_as_uint(r.x) == SENTU || __float_as_uint(r.y) == SENTU ||
           __float_as_uint(r.z) == SENTU || __float_as_uint(r.w) == SENTU)
        r = ld_cg4(p);
    return r;
}
__device__ __forceinline__ void ld_cg16(const float* p, f32x4& a, f32x4& b, f32x4& c, f32x4& d) {
    asm volatile("global_load_dwordx4 %0, %4, off sc0 sc1\n\t"
                 "global_load_dwordx4 %1, %5, off sc0 sc1\n\t"
                 "global_load_dwordx4 %2, %6, off sc0 sc1\n\t"
                 "global_load_dwordx4 %3, %7, off sc0 sc1\n\t"
                 "s_waitcnt vmcnt(0)"
                 : "=&v"(a), "=&v"(b), "=&v"(c), "=&v"(d)
                 : "v"(p), "v"(p+4), "v"(p+8), "v"(p+12) : "memory");
}
__device__ __forceinline__ bool anynan(f32x4 v) {
    return __float_as_uint(v.x) == SENTU || __float_as_uint(v.y) == SENTU ||
           __float_as_uint(v.z) == SENTU || __float_as_uint(v.w) == SENTU;
}
// packed 64B publish (4x16B stores; vmcnt drain first orders prior resets)
__device__ __forceinline__ void st_pub16(float* p, f32x4 a, f32x4 b, f32x4 c, f32x4 d) {
    asm volatile("s_waitcnt vmcnt(0)\n\t"
                 "global_store_dwordx4 %0, %4, off sc0 sc1\n\t"
                 "global_store_dwordx4 %1, %5, off sc0 sc1\n\t"
                 "global_store_dwordx4 %2, %6, off sc0 sc1\n\t"
                 "global_store_dwordx4 %3, %7, off sc0 sc1"
                 :: "v"(p), "v"(p+4), "v"(p+8), "v"(p+12),
                    "v"(a), "v"(b), "v"(c), "v"(d) : "memory");
}
__device__ __forceinline__ void st_rst16(float* p) {
    f32x4 s; s.x = s.y = s.z = s.w = __uint_as_float(SENTU);
    asm volatile("global_store_dwordx4 %0, %4, off sc0 sc1\n\t"
                 "global_store_dwordx4 %1, %4, off sc0 sc1\n\t"
                 "global_store_dwordx4 %2, %4, off sc0 sc1\n\t"
                 "global_store_dwordx4 %3, %4, off sc0 sc1"
                 :: "v"(p), "v"(p+4), "v"(p+8), "v"(p+12), "v"(s) : "memory");
}
__device__ __forceinline__ void st_pub1(float* p, float x) {
    asm volatile("s_waitcnt vmcnt(0)\n\tglobal_store_dword %0, %1, off sc0 sc1"
                 :: "v"(p), "v"(x) : "memory");
}
__device__ __forceinline__ void st_rst1(float* p) {
    float v = __uint_as_float(SENTU);
    asm volatile("global_store_dword %0, %1, off sc0 sc1" :: "v"(p), "v"(v) : "memory");
}

__global__ void init_ex(unsigned* p, int n) {
    int i = blockIdx.x * blockDim.x + threadIdx.x;
    if (i < n) p[i] = SENTU;
}

// ---------------- generic NT GEMM (unchanged) ----------------
__global__ __launch_bounds__(256) void gemm_nt(
    const float* __restrict__ Amat, int lda,
    const float* __restrict__ Bmat, int ldb,
    float* __restrict__ C, int ldc,
    const float* __restrict__ bias, int M, int N, int K)
{
    __shared__ float As[16][68];
    __shared__ float Bs[16][68];
    const int tid = threadIdx.x;
    const int tx = tid & 15;
    const int ty = tid >> 4;
    const int m0 = blockIdx.y * 64;
    const int n0 = blockIdx.x * 64;
    const int lr = tid >> 2;
    const int lk = (tid & 3) * 4;

    float acc[4][4] = {};
    for (int k0 = 0; k0 < K; k0 += 16) {
        float4 av = *(const float4*)(Amat + (size_t)(m0 + lr) * lda + k0 + lk);
        float4 bv = *(const float4*)(Bmat + (size_t)(n0 + lr) * ldb + k0 + lk);
        __syncthreads();
        As[lk+0][lr] = av.x; As[lk+1][lr] = av.y; As[lk+2][lr] = av.z; As[lk+3][lr] = av.w;
        Bs[lk+0][lr] = bv.x; Bs[lk+1][lr] = bv.y; Bs[lk+2][lr] = bv.z; Bs[lk+3][lr] = bv.w;
        __syncthreads();
        #pragma unroll
        for (int k = 0; k < 16; ++k) {
            float a4[4], b4[4];
            #pragma unroll
            for (int i = 0; i < 4; ++i) a4[i] = As[k][ty*4+i];
            #pragma unroll
            for (int j = 0; j < 4; ++j) b4[j] = Bs[k][tx*4+j];
            #pragma unroll
            for (int i = 0; i < 4; ++i)
                #pragma unroll
                for (int j = 0; j < 4; ++j) acc[i][j] += a4[i] * b4[j];
        }
    }
    #pragma unroll
    for (int i = 0; i < 4; ++i) {
        const int m = m0 + ty*4 + i;
        #pragma unroll
        for (int j = 0; j < 4; ++j) {
            const int n = n0 + tx*4 + j;
            float v = acc[i][j];
            if (bias) v += bias[n];
            C[(size_t)m * ldc + n] = v;
        }
    }
}

// ---------------- persistent encoder scan: block-packed 64B h-chunks ----------------
__global__ __launch_bounds__(NTHR, 2) void enc_scan(
    const float* __restrict__ W_enc, const float* __restrict__ accx,
    float* __restrict__ states, float* __restrict__ hex)
{
    __shared__ __align__(16) float hs[H];
    __shared__ __align__(16) float hout[16];
    const int tid = threadIdx.x;
    const int wid = tid >> 6, lane = tid & 63;
    const int bid = blockIdx.x;
    const int w   = bid * 8 + wid;            // 0..1023, rows 2w,2w+1 (block: rows 16b..16b+15)
    const int r0  = 2*w, r1 = r0 + 1;

    f32x4 we0[8], we1[8];
    #pragma unroll
    for (int k = 0; k < 8; ++k) {
        we0[k] = *(const f32x4*)(W_enc + (size_t)r0*(V+H) + V + 4*(lane + 64*k));
        we1[k] = *(const f32x4*)(W_enc + (size_t)r1*(V+H) + V + 4*(lane + 64*k));
    }

    // t = 0: h = tanh(accx)
    {
        float h0 = tanhf(accx[r0]), h1 = tanhf(accx[r1]);
        if (lane == 0) { hout[2*wid] = h0; hout[2*wid+1] = h1; }
        __syncthreads();
        if (tid == 0) {
            const f32x4* g = (const f32x4*)hout;
            st_pub16(hex + 0*HPH + bid*CH, g[0], g[1], g[2], g[3]);
        }
        if (lane == 0) { states[r0] = h0; states[r1] = h1; }
    }

    for (int t = 1; t < S; ++t) {
        float ax0 = accx[(size_t)t*H + r0];   // broadcast L2-hit loads
        float ax1 = accx[(size_t)t*H + r1];
        // poll packed h_{t-1}: threads 0..127 poll 64B chunk tid
        if (tid < 128) {
            const float* cp = hex + ((t-1)%3)*HPH + tid*CH;
            f32x4 a, b, c, d;
            do { ld_cg16(cp, a, b, c, d); } while (anynan(a)||anynan(b)||anynan(c)||anynan(d));
            f32x4* dst = (f32x4*)(hs + 16*tid);
            dst[0] = a; dst[1] = b; dst[2] = c; dst[3] = d;
        }
        __syncthreads();
        // reset own chunk of phase t+1 (proven consumed); drains during the dot
        if (tid == 0) st_rst16(hex + ((t+1)%3)*HPH + bid*CH);

        const f32x4* h4 = (const f32x4*)hs;
        float a0 = 0.f, a1 = 0.f;
        #pragma unroll
        for (int k = 0; k < 8; ++k) {
            f32x4 hv = h4[lane + 64*k];
            a0 += we0[k].x*hv.x + we0[k].y*hv.y + we0[k].z*hv.z + we0[k].w*hv.w;
            a1 += we1[k].x*hv.x + we1[k].y*hv.y + we1[k].z*hv.z + we1[k].w*hv.w;
        }
        #pragma unroll
        for (int off = 32; off; off >>= 1) { a0 += __shfl_down(a0, off); a1 += __shfl_down(a1, off); }
        float h0 = 0.f, h1 = 0.f;
        if (lane == 0) {
            h0 = tanhf(a0 + ax0); h1 = tanhf(a1 + ax1);
            hout[2*wid] = h0; hout[2*wid+1] = h1;
        }
        __syncthreads();
        if (tid == 0) {
            const f32x4* g = (const f32x4*)hout;
            st_pub16(hex + (t%3)*HPH + bid*CH, g[0], g[1], g[2], g[3]);
        }
        if (lane == 0) {                      // off critical path
            states[(size_t)t*H + r0] = h0; states[(size_t)t*H + r1] = h1;
        }
    }
}

// ---------------- persistent decoder scan: packed h, R7 dp/e, 3 hops/step ----------------
__global__ __launch_bounds__(NTHR, 2) void dec_scan(
    const float* __restrict__ Wa_dec, const float* __restrict__ W_dec,
    const float* __restrict__ enc_proj, const float* __restrict__ v_a,
    const float* __restrict__ WcT, const float* __restrict__ accx,
    const float* __restrict__ enc_states, float* __restrict__ h_dec,
    float* __restrict__ hexd, float* __restrict__ dpex, float* __restrict__ eex)
{
    __shared__ __align__(16) float hs[H];
    __shared__ __align__(16) float ps[A];
    __shared__ __align__(16) float es[S];
    __shared__ __align__(16) float hout[16];
    __shared__ float zred[8];
    const int tid = threadIdx.x;
    const int wid = tid >> 6, lane = tid & 63;
    const int bid = blockIdx.x;
    const int w   = bid * 8 + wid;            // 0..1023, rows 2w,2w+1
    const int r0  = 2*w, r1 = r0 + 1;
    const bool attn = ((w & 1) == 0);         // even waves own attn row s_row = w>>1
    const int s_row = w >> 1;
    const int aslot = (s_row >> 2)*CH + (s_row & 3);   // word in dp/e 16B chunk

    f32x4 wh0[8], wh1[8], wa[8], wc0[2], wc1[2], ep[2], va[2];
    #pragma unroll
    for (int k = 0; k < 8; ++k) {
        wh0[k] = *(const f32x4*)(W_dec + (size_t)r0*(V+2*H) + V + H + 4*(lane + 64*k));
        wh1[k] = *(const f32x4*)(W_dec + (size_t)r1*(V+2*H) + V + H + 4*(lane + 64*k));
        wa[k]  = (f32x4)(0.f);
    }
    #pragma unroll
    for (int k = 0; k < 2; ++k) {
        wc0[k] = *(const f32x4*)(WcT + (size_t)r0*S + 4*(lane + 64*k));
        wc1[k] = *(const f32x4*)(WcT + (size_t)r1*S + 4*(lane + 64*k));
        ep[k] = (f32x4)(0.f); va[k] = (f32x4)(0.f);
    }
    if (attn) {
        #pragma unroll
        for (int k = 0; k < 8; ++k)
            wa[k] = *(const f32x4*)(Wa_dec + (size_t)s_row*H + 4*(lane + 64*k));
        #pragma unroll
        for (int k = 0; k < 2; ++k) {
            ep[k] = *(const f32x4*)(enc_proj + (size_t)s_row*A + 4*(lane + 64*k));
            va[k] = *(const f32x4*)(v_a + 4*(lane + 64*k));
        }
    }
    const f32x4* hs4 = (const f32x4*)hs;
    const f32x4* ps4 = (const f32x4*)ps;
    const f32x4* es4 = (const f32x4*)es;

    for (int t = 0; t < S; ++t) {
        const int ph  = t % 3;
        const int phn = (t+1) % 3;
        const int php = (t+2) % 3;   // == (t-1)%3

        float ax0 = accx[(size_t)t*H + r0];
        float ax1 = accx[(size_t)t*H + r1];

        // ---- A: stage h_{t-1} ----
        if (t == 0) {
            ((f32x4*)hs)[tid] = ((const f32x4*)(enc_states + (size_t)(S-1)*H))[tid];
        } else if (tid < 128) {
            const float* cp = hexd + php*HPH + tid*CH;
            f32x4 a, b, c, d;
            do { ld_cg16(cp, a, b, c, d); } while (anynan(a)||anynan(b)||anynan(c)||anynan(d));
            f32x4* dst = (f32x4*)(hs + 16*tid);
            dst[0] = a; dst[1] = b; dst[2] = c; dst[3] = d;
        }
        __syncthreads();                                   // sync1

        // resets (proven-consumed phases; drain during compute)
        if (tid == 0) st_rst16(hexd + phn*HPH + bid*CH);
        if (t > 0 && attn && lane == 0) {
            st_rst1(dpex + php*DPH + aslot);
            st_rst1(eex  + php*DPH + aslot);
        }

        // ---- B: attn waves publish dec_proj word ASAP, then all W_h dots ----
        if (attn) {
            float aP = 0.f;
            #pragma unroll
            for (int k = 0; k < 8; ++k) {
                f32x4 hv = hs4[lane + 64*k];
                aP += wa[k].x*hv.x + wa[k].y*hv.y + wa[k].z*hv.z + wa[k].w*hv.w;
            }
            #pragma unroll
            for (int off = 32; off; off >>= 1) aP += __shfl_down(aP, off);
            if (lane == 0) st_pub1(dpex + ph*DPH + aslot, aP);
        }
        float aH0 = 0.f, aH1 = 0.f;
        #pragma unroll
        for (int k = 0; k < 8; ++k) {
            f32x4 hv = hs4[lane + 64*k];
            aH0 += wh0[k].x*hv.x + wh0[k].y*hv.y + wh0[k].z*hv.z + wh0[k].w*hv.w;
            aH1 += wh1[k].x*hv.x + wh1[k].y*hv.y + wh1[k].z*hv.z + wh1[k].w*hv.w;
        }
        #pragma unroll
        for (int off = 32; off; off >>= 1) { aH0 += __shfl_down(aH0, off); aH1 += __shfl_down(aH1, off); }

        // ---- C: threads 0..127 poll dp chunks; attn waves compute+publish e ----
        if (tid < 128) ((f32x4*)ps)[tid] = poll4(dpex + ph*DPH + tid*CH);
        __syncthreads();                                   // sync2
        if (attn) {
            float e_ = 0.f;
            #pragma unroll
            for (int k = 0; k < 2; ++k) {
                f32x4 p = ps4[lane + 64*k];
                e_ += va[k].x*tanhf(ep[k].x + p.x) + va[k].y*tanhf(ep[k].y + p.y)
                    + va[k].z*tanhf(ep[k].z + p.z) + va[k].w*tanhf(ep[k].w + p.w);
            }
            #pragma unroll
            for (int off = 32; off; off >>= 1) e_ += __shfl_down(e_, off);
            if (lane == 0) st_pub1(eex + ph*DPH + aslot, expf(e_));
        }

        // ---- D: threads 0..127 poll e chunks ----
        if (tid < 128) ((f32x4*)es)[tid] = poll4(eex + ph*DPH + tid*CH);
        __syncthreads();                                   // syncD

        // ---- E: Z, ctx, h_new, packed publish ----
        float z = es[tid];
        #pragma unroll
        for (int off = 32; off; off >>= 1) z += __shfl_down(z, off);
        if (lane == 0) zred[wid] = z;
        __syncthreads();                                   // syncZ
        const float Z = zred[0]+zred[1]+zred[2]+zred[3]+zred[4]+zred[5]+zred[6]+zred[7];

        float c0 = 0.f, c1 = 0.f;
        #pragma unroll
        for (int k = 0; k < 2; ++k) {
            f32x4 ev = es4[lane + 64*k];
            c0 += wc0[k].x*ev.x + wc0[k].y*ev.y + wc0[k].z*ev.z + wc0[k].w*ev.w;
            c1 += wc1[k].x*ev.x + wc1[k].y*ev.y + wc1[k].z*ev.z + wc1[k].w*ev.w;
        }
        #pragma unroll
        for (int off = 32; off; off >>= 1) { c0 += __shfl_down(c0, off); c1 += __shfl_down(c1, off); }

        float h0 = 0.f, h1 = 0.f;
        if (lane == 0) {
            const float Zi = 1.f / Z;
            h0 = tanhf(ax0 + aH0 + c0*Zi);
            h1 = tanhf(ax1 + aH1 + c1*Zi);
            hout[2*wid] = h0; hout[2*wid+1] = h1;
        }
        __syncthreads();                                   // syncE (gather)
        if (tid == 0) {
            const f32x4* g = (const f32x4*)hout;
            st_pub16(hexd + ph*HPH + bid*CH, g[0], g[1], g[2], g[3]);
        }
        if (lane == 0) {                                   // off critical path
            f32x2 hv; hv.x = h0; hv.y = h1;
            *(f32x2*)(h_dec + (size_t)t*H + r0) = hv;
        }
    }
}

extern "C" void kernel_launch(void* const* d_in, const int* in_sizes, int n_in,
                              void* d_out, int out_size, void* d_ws, size_t ws_size,
                              hipStream_t stream) {
    const float* x_enc  = (const float*)d_in[0];
    const float* x_dec  = (const float*)d_in[1];
    const float* W_enc  = (const float*)d_in[2];
    const float* b_enc  = (const float*)d_in[3];
    const float* Wa_enc = (const float*)d_in[4];
    const float* Wa_dec = (const float*)d_in[5];
    const float* v_a    = (const float*)d_in[6];
    const float* W_dec  = (const float*)d_in[7];
    const float* b_dec  = (const float*)d_in[8];
    const float* W_out  = (const float*)d_in[9];
    const float* b_out  = (const float*)d_in[10];
    float* out = (float*)d_out;

    float* ws         = (float*)d_ws;
    float* accx_enc   = ws;                          // S*H
    float* enc_states = accx_enc + (size_t)S*H;      // S*H
    float* enc_proj   = enc_states + (size_t)S*H;    // S*A
    float* WcT        = enc_proj + (size_t)S*A;      // H*S
    float* accx_dec   = WcT + (size_t)H*S;           // S*H
    float* h_dec      = accx_dec + (size_t)S*H;      // S*H
    float* hex_e      = h_dec + (size_t)S*H;         // 3*HPH
    float* hex_d      = hex_e + 3*HPH;               // 3*HPH
    float* dp_ex      = hex_d + 3*HPH;               // 3*DPH
    float* e_ex       = dp_ex + 3*DPH;               // 3*DPH
    const int n_ex = 3*HPH*2 + 3*DPH*2;

    dim3 b256(256);

    init_ex<<<dim3((n_ex + 255)/256), b256, 0, stream>>>((unsigned*)hex_e, n_ex);

    // accx_enc = x_enc @ W_enc[:, :V].T + b_enc
    gemm_nt<<<dim3(H/64, S/64), b256, 0, stream>>>(x_enc, V, W_enc, V+H, accx_enc, H, b_enc, S, H, V);
    // accx_dec = x_dec @ W_dec[:, :V].T + b_dec
    gemm_nt<<<dim3(H/64, S/64), b256, 0, stream>>>(x_dec, V, W_dec, V+2*H, accx_dec, H, b_dec, S, H, V);

    // encoder scan
    {
        const float* We = W_enc; const float* ax = accx_enc; float* st = enc_states; float* hx = hex_e;
        void* args[] = { &We, &ax, &st, &hx };
        hipLaunchCooperativeKernel((void*)enc_scan, dim3(NBLK), dim3(NTHR), args, 0, stream);
    }

    // enc_proj = enc_states @ Wa_enc.T
    gemm_nt<<<dim3(A/64, S/64), b256, 0, stream>>>(enc_states, H, Wa_enc, H, enc_proj, A, nullptr, S, A, H);
    // WcT[i][s] = W_c[i]·enc_states[s]
    gemm_nt<<<dim3(S/64, H/64), b256, 0, stream>>>(W_dec + V, V+2*H, enc_states, H, WcT, S, nullptr, H, S, H);

    // decoder scan
    {
        const float* wa = Wa_dec; const float* wd = W_dec; const float* epj = enc_proj;
        const float* vv = v_a; const float* wc = WcT; const float* ax = accx_dec;
        const float* est = enc_states; float* hd = h_dec;
        float* hx = hex_d; float* dx = dp_ex; float* ex = e_ex;
        void* args[] = { &wa, &wd, &epj, &vv, &wc, &ax, &est, &hd, &hx, &dx, &ex };
        hipLaunchCooperativeKernel((void*)dec_scan, dim3(NBLK), dim3(NTHR), args, 0, stream);
    }

    // logits = h_dec @ W_out.T + b_out
    gemm_nt<<<dim3(V/64, S/64), b256, 0, stream>>>(h_dec, H, W_out, H, out, V, b_out, S, V, H);
}